// Round 8
// baseline (212.574 us; speedup 1.0000x reference)
//
#include <hip/hip_runtime.h>

#define H    128
#define NB   4
#define NPB  16    // dst-nodes per block in fused kernel

typedef __attribute__((ext_vector_type(8))) short short8;
typedef __attribute__((ext_vector_type(4))) float f32x4;

static __device__ __forceinline__ unsigned short f2bf(float f) {
    unsigned u = __float_as_uint(f);
    unsigned r = (u + 0x7fffu + ((u >> 16) & 1u)) >> 16;
    return (unsigned short)r;
}
static __device__ __forceinline__ float bf_lo(unsigned v) {
    return __uint_as_float((v & 0xffffu) << 16);
}
static __device__ __forceinline__ float bf_hi(unsigned v) {
    return __uint_as_float(v & 0xffff0000u);
}

// ---------------- zero int array ----------------
__global__ __launch_bounds__(256) void zero_i(int* __restrict__ p, int n) {
    int i = blockIdx.x * 256 + threadIdx.x;
    if (i < n) p[i] = 0;
}

// ------- histogram + per-edge arrival rank -------
__global__ __launch_bounds__(256) void hist_rank(const int* __restrict__ dst,
                                                 int* __restrict__ counts,
                                                 int* __restrict__ rank, int E) {
    int e = blockIdx.x * 256 + threadIdx.x;
    if (e < E) rank[e] = atomicAdd(&counts[dst[e]], 1);
}

// ---------------- hierarchical scan stage 1 ----------------
__global__ __launch_bounds__(1024) void scan_blocks(const int* __restrict__ counts,
                                                    int* __restrict__ partial,
                                                    int* __restrict__ blocksums, int n) {
    __shared__ int buf[1024];
    int tid = threadIdx.x;
    int i = blockIdx.x * 1024 + tid;
    buf[tid] = (i < n) ? counts[i] : 0;
    __syncthreads();
#pragma unroll
    for (int off = 1; off < 1024; off <<= 1) {
        int t = (tid >= off) ? buf[tid - off] : 0;
        __syncthreads();
        buf[tid] += t;
        __syncthreads();
    }
    if (i < n) partial[i] = buf[tid];
    if (tid == 1023) blocksums[blockIdx.x] = buf[1023];
}

// ---------------- stage 2: single-wave scan of block sums (nb <= 64) ----------------
__global__ __launch_bounds__(64) void scan_carry(int* __restrict__ blocksums, int nb) {
    int tid = threadIdx.x;
    int v = (tid < nb) ? blocksums[tid] : 0;
#pragma unroll
    for (int off = 1; off < 64; off <<= 1) {
        int t = __shfl_up(v, off);
        if (tid >= off) v += t;
    }
    if (tid < nb) blocksums[tid] = v;
}

// ---------------- stage 3: add carry, emit offs[0..n] ----------------
__global__ __launch_bounds__(256) void scan_add(const int* __restrict__ partial,
                                                const int* __restrict__ blocksums,
                                                int* __restrict__ offs, int n) {
    int i = blockIdx.x * 256 + threadIdx.x;
    if (i >= n) return;
    int b = i >> 10;
    int carry = (b > 0) ? blocksums[b - 1] : 0;
    offs[i + 1] = partial[i] + carry;
    if (i == 0) offs[0] = 0;
}

// ------- scatter edges into CSR (rank-based); 16B edge records per layer -------
// rec = {src, w[0..1] packed bf16, w[2..3] packed bf16, 0} where w = norm*comp[etype]
__global__ __launch_bounds__(256) void scatter_edges(
        const int* __restrict__ src, const int* __restrict__ dst,
        const int* __restrict__ etype, const float* __restrict__ norm,
        const float* __restrict__ comp0, const float* __restrict__ comp1,
        const int* __restrict__ offs, const int* __restrict__ rank,
        uint4* __restrict__ er0, uint4* __restrict__ er1, int E) {
    int e = blockIdx.x * 256 + threadIdx.x;
    if (e >= E) return;
    int pos = offs[dst[e]] + rank[e];
    float w = norm[e];
    int et = etype[e];
    float4 c0 = *(const float4*)(comp0 + et * NB);
    float4 c1 = *(const float4*)(comp1 + et * NB);
    uint4 r0, r1;
    r0.x = (unsigned)src[e];
    r0.y = (unsigned)f2bf(w * c0.x) | ((unsigned)f2bf(w * c0.y) << 16);
    r0.z = (unsigned)f2bf(w * c0.z) | ((unsigned)f2bf(w * c0.w) << 16);
    r0.w = 0;
    r1.x = (unsigned)src[e];
    r1.y = (unsigned)f2bf(w * c1.x) | ((unsigned)f2bf(w * c1.y) << 16);
    r1.z = (unsigned)f2bf(w * c1.z) | ((unsigned)f2bf(w * c1.w) << 16);
    r1.w = 0;
    er0[pos] = r0;
    er1[pos] = r1;
}

// ---------------- f32 -> bf16 convert ----------------
__global__ __launch_bounds__(256) void convert_bf16(const float* __restrict__ in,
                                                    unsigned short* __restrict__ out, int n4) {
    int i = blockIdx.x * 256 + threadIdx.x;
    if (i >= n4) return;
    float4 v = ((const float4*)in)[i];
    ushort4 o;
    o.x = f2bf(v.x); o.y = f2bf(v.y); o.z = f2bf(v.z); o.w = f2bf(v.w);
    ((ushort4*)out)[i] = o;
}

// ---- Wb build: Wb[l][o][b*128+d] = bf16(basis_l[b][d][o])  (pure transpose) ----
__global__ __launch_bounds__(128) void make_wb(
        const float* __restrict__ basis0, const float* __restrict__ basis1,
        unsigned short* __restrict__ Wb) {
    int b = blockIdx.x;        // 0..3
    int d = blockIdx.y;        // 0..127
    int l = blockIdx.z;        // 0..1
    int o = threadIdx.x;       // 0..127
    const float* basis = l ? basis1 : basis0;
    float s = basis[((size_t)b * H + d) * H + o];
    Wb[((size_t)l * H + o) * (NB * H) + b * H + d] = f2bf(s);
}

// ---------------- fused layer: basis-agg (LDS) + MFMA GEMM + bias + relu ----------------
// block = 512 threads (8 waves), NPB=16 dst nodes, K = NB*H = 512.
// Phase A: thread = (node nl = tid>>5, chunk ch = tid&31, 4 channels).
//          Edge recs staged to LDS in coalesced 32-edge bursts; unroll-4 gathers
//          (8B each) kept in flight via distinct registers. 16 f32 acc/thread.
// Phase B: wave w computes output cols [w*16, w*16+16) for all 16 rows.
#define EACC(R, HV) {                                                   \
    float f0 = bf_lo(HV.x), f1 = bf_hi(HV.x);                           \
    float f2 = bf_lo(HV.y), f3 = bf_hi(HV.y);                           \
    float wa = bf_lo(R.y), wb = bf_hi(R.y);                             \
    float wc = bf_lo(R.z), wd = bf_hi(R.z);                             \
    a0[0] = fmaf(wa, f0, a0[0]); a0[1] = fmaf(wa, f1, a0[1]);           \
    a0[2] = fmaf(wa, f2, a0[2]); a0[3] = fmaf(wa, f3, a0[3]);           \
    a1[0] = fmaf(wb, f0, a1[0]); a1[1] = fmaf(wb, f1, a1[1]);           \
    a1[2] = fmaf(wb, f2, a1[2]); a1[3] = fmaf(wb, f3, a1[3]);           \
    a2[0] = fmaf(wc, f0, a2[0]); a2[1] = fmaf(wc, f1, a2[1]);           \
    a2[2] = fmaf(wc, f2, a2[2]); a2[3] = fmaf(wc, f3, a2[3]);           \
    a3[0] = fmaf(wd, f0, a3[0]); a3[1] = fmaf(wd, f1, a3[1]);           \
    a3[2] = fmaf(wd, f2, a3[2]); a3[3] = fmaf(wd, f3, a3[3]); }

__global__ __launch_bounds__(512, 8) void fused_layer(
        const unsigned short* __restrict__ hin,   // [M][128] bf16
        const int* __restrict__ offs,             // [M+1]
        const uint4* __restrict__ er,             // 16B edge records (this layer)
        const unsigned short* __restrict__ Wb,    // [128 o][512 k] bf16
        const float* __restrict__ bias,
        void* __restrict__ outp, int M, int write_bf16) {
    __shared__ unsigned short tile[NPB][512];     // 16 KB agg tile (swizzled rows)
    __shared__ uint4 recs[NPB][32];               // 8 KB staged edge records
    const int tid = threadIdx.x;
    const int nl  = tid >> 5;      // local node 0..15
    const int ch  = tid & 31;      // 8B chunk of the 256B row
    const int v0  = blockIdx.x * NPB;
    const int v   = v0 + nl;

    // ---------------- phase A ----------------
    float a0[4], a1[4], a2[4], a3[4];
#pragma unroll
    for (int c = 0; c < 4; ++c) { a0[c] = 0.f; a1[c] = 0.f; a2[c] = 0.f; a3[c] = 0.f; }

    if (v < M) {
        const int beg = offs[v], end = offs[v + 1];
        for (int base = beg; base < end; base += 32) {
            const int cnt = min(32, end - base);
            if (ch < cnt) recs[nl][ch] = er[base + ch];   // coalesced 512B burst
            int j = 0;
            for (; j + 4 <= cnt; j += 4) {
                uint4 r0 = recs[nl][j];
                uint4 r1 = recs[nl][j + 1];
                uint4 r2 = recs[nl][j + 2];
                uint4 r3 = recs[nl][j + 3];
                uint2 h0 = *(const uint2*)(hin + (size_t)r0.x * H + ch * 4);
                uint2 h1 = *(const uint2*)(hin + (size_t)r1.x * H + ch * 4);
                uint2 h2 = *(const uint2*)(hin + (size_t)r2.x * H + ch * 4);
                uint2 h3 = *(const uint2*)(hin + (size_t)r3.x * H + ch * 4);
                EACC(r0, h0) EACC(r1, h1) EACC(r2, h2) EACC(r3, h3)
            }
            for (; j < cnt; ++j) {
                uint4 r0 = recs[nl][j];
                uint2 h0 = *(const uint2*)(hin + (size_t)r0.x * H + ch * 4);
                EACC(r0, h0)
            }
        }
    }

    // write agg tile row nl: 4 bases x 8B (packed bf16), swizzled
    {
        char* row = (char*)tile[nl];
        const int swz = (nl & 7) << 4;
#define PUT(B, A) { uint2 pk; \
        pk.x = (unsigned)f2bf(A[0]) | ((unsigned)f2bf(A[1]) << 16); \
        pk.y = (unsigned)f2bf(A[2]) | ((unsigned)f2bf(A[3]) << 16); \
        *(uint2*)(row + ((B * 256 + ch * 8) ^ swz)) = pk; }
        PUT(0, a0) PUT(1, a1) PUT(2, a2) PUT(3, a3)
#undef PUT
    }
    __syncthreads();

    // ---------------- phase B: [16 x 512] @ [512 x 128] ----------------
    const int wid  = tid >> 6;
    const int lane = tid & 63;
    const int n0 = wid * 16;           // this wave's 16 output cols
    const int lr = lane & 15;
    const int lg = lane >> 4;
    const char* bbase = (const char*)Wb + (size_t)(n0 + lr) * (NB * H) * 2;
    const char* abase = (const char*)tile + lr * 1024;
    const int swz = (lr & 7) << 4;

    f32x4 acc = (f32x4){0.f, 0.f, 0.f, 0.f};
#pragma unroll
    for (int ks = 0; ks < 16; ++ks) {
        const int kb = ks * 64 + lg * 16;
        short8 b = *(const short8*)(bbase + kb);
        short8 a = *(const short8*)(abase + (kb ^ swz));
        acc = __builtin_amdgcn_mfma_f32_16x16x32_bf16(a, b, acc, 0, 0, 0);
    }

    const float bcol = bias[n0 + lr];
#pragma unroll
    for (int j = 0; j < 4; ++j) {
        const int grow = v0 + lg * 4 + j;
        if (grow < M) {
            float val = fmaxf(acc[j] + bcol, 0.f);
            if (write_bf16)
                ((unsigned short*)outp)[(size_t)grow * H + n0 + lr] = f2bf(val);
            else
                ((float*)outp)[(size_t)grow * H + n0 + lr] = val;
        }
    }
}

extern "C" void kernel_launch(void* const* d_in, const int* in_sizes, int n_in,
                              void* d_out, int out_size, void* d_ws, size_t ws_size,
                              hipStream_t stream) {
    const float* feats  = (const float*)d_in[0];
    const int*   src    = (const int*)  d_in[1];
    const int*   dst    = (const int*)  d_in[2];
    const int*   etype  = (const int*)  d_in[3];
    const float* norm   = (const float*)d_in[4];
    const float* basis0 = (const float*)d_in[5];
    const float* comp0  = (const float*)d_in[6];
    const float* bias0  = (const float*)d_in[7];
    const float* basis1 = (const float*)d_in[8];
    const float* comp1  = (const float*)d_in[9];
    const float* bias1  = (const float*)d_in[10];
    float* out = (float*)d_out;

    const int M = in_sizes[0] / H;     // 50000
    const int E = in_sizes[1];         // 600000

    // workspace carve-up (256B aligned)
    char* ws = (char*)d_ws;
    size_t cur = 0;
    auto take = [&](size_t bytes) { void* p = ws + cur; cur += (bytes + 255) & ~(size_t)255; return p; };
    unsigned short* hbf  = (unsigned short*)take((size_t)M * H * 2);           // 12.8 MB
    unsigned short* h1bf = (unsigned short*)take((size_t)M * H * 2);           // 12.8 MB
    unsigned short* Wb   = (unsigned short*)take((size_t)2 * H * NB * H * 2);  // 256 KB
    int*   counts  = (int*)take((size_t)M * 4);
    int*   offs    = (int*)take((size_t)(M + 1) * 4);
    int*   partial = (int*)take((size_t)M * 4);
    int*   bsums   = (int*)take((size_t)64 * 4);
    int*   rank    = (int*)take((size_t)E * 4);
    uint4* er0     = (uint4*)take((size_t)E * 16);                             // 9.6 MB
    uint4* er1     = (uint4*)take((size_t)E * 16);                             // 9.6 MB

    dim3 blk(256);
    int mb  = (M + 255) / 256;
    int eb  = (E + 255) / 256;
    int n4  = M * H / 4;
    int cb  = (n4 + 255) / 256;
    int nsb = (M + 1023) / 1024;         // 49 <= 64
    int fb  = (M + NPB - 1) / NPB;       // 3125

    // ---- graph prep (stateless every call, single CSR build) ----
    zero_i       <<<mb, blk, 0, stream>>>(counts, M);
    hist_rank    <<<eb, blk, 0, stream>>>(dst, counts, rank, E);
    scan_blocks  <<<nsb, 1024, 0, stream>>>(counts, partial, bsums, M);
    scan_carry   <<<1, 64, 0, stream>>>(bsums, nsb);
    scan_add     <<<mb, blk, 0, stream>>>(partial, bsums, offs, M);
    scatter_edges<<<eb, blk, 0, stream>>>(src, dst, etype, norm, comp0, comp1,
                                          offs, rank, er0, er1, E);
    convert_bf16 <<<cb, blk, 0, stream>>>(feats, hbf, n4);
    make_wb      <<<dim3(NB, H, 2), 128, 0, stream>>>(basis0, basis1, Wb);

    // ---- layer 0 ----
    fused_layer<<<fb, 512, 0, stream>>>(hbf, offs, er0, Wb, bias0, h1bf, M, 1);
    // ---- layer 1 ----
    fused_layer<<<fb, 512, 0, stream>>>(h1bf, offs, er1,
                                        Wb + (size_t)H * NB * H, bias1, out, M, 0);
}